// Round 1
// baseline (153.924 us; speedup 1.0000x reference)
//
#include <hip/hip_runtime.h>
#include <stdint.h>
#include <math.h>

#define NROWS 8192
#define DDIM  256
#define BM    128
#define BN    128
#define GJ    8                         // column groups (grid.y)
#define COLS_PER_GROUP (NROWS / GJ)     // 1024
#define QSTR  264                       // lds Q row stride (bf16 elems): 528B, 16B-aligned, 2-way banks (free)
#define KSTR  40                        // lds K row stride: 80B, 16B-aligned, 2-way banks

constexpr float INV_T      = 1.0f / 0.07f;
constexpr float DIAG_LOGIT = -10.0f / 0.07f;

typedef __bf16 bf16x8 __attribute__((ext_vector_type(8)));
typedef float  f32x4  __attribute__((ext_vector_type(4)));

__device__ inline uint16_t f2bf(float f) {
    uint32_t u = __float_as_uint(f);
    u += 0x7fffu + ((u >> 16) & 1u);    // RNE
    return (uint16_t)(u >> 16);
}

// Kernel 1: per-row reciprocal norms + bf16 conversion for both inputs.
// One wave per row (256 cols / 64 lanes = float4 per lane). 2N rows total.
__global__ __launch_bounds__(256) void norm_convert_kernel(
    const float* __restrict__ fq, const float* __restrict__ fk,
    uint16_t* __restrict__ qb, uint16_t* __restrict__ kb,
    float* __restrict__ rnq, float* __restrict__ rnk)
{
    const int wave = threadIdx.x >> 6;
    const int lane = threadIdx.x & 63;
    const int row  = blockIdx.x * 4 + wave;

    const float* src; uint16_t* dstb; float* dstr;
    if (row < NROWS) {
        src = fq + (size_t)row * DDIM; dstb = qb + (size_t)row * DDIM; dstr = rnq + row;
    } else {
        int r = row - NROWS;
        src = fk + (size_t)r * DDIM; dstb = kb + (size_t)r * DDIM; dstr = rnk + r;
    }

    float4 v = ((const float4*)src)[lane];
    float ss = v.x*v.x + v.y*v.y + v.z*v.z + v.w*v.w;
    #pragma unroll
    for (int m = 1; m < 64; m <<= 1) ss += __shfl_xor(ss, m, 64);
    if (lane == 0) *dstr = rsqrtf(ss);  // norms ~16 for N(0,1) D=256; eps clamp unreachable

    ushort4 o;
    o.x = f2bf(v.x); o.y = f2bf(v.y); o.z = f2bf(v.z); o.w = f2bf(v.w);
    ((ushort4*)dstb)[lane] = o;
}

// Kernel 2: fused  S = (Q K^T) * rnq * rnk * (1/T)  with diag -> -10/T,
// online logsumexp per row over this block's 1024-column group.
// Block: 256 thr = 4 waves in 2x2 grid; each wave computes 64x64 via 16x16x32 bf16 MFMA.
__global__ __launch_bounds__(256, 2) void nce_main_kernel(
    const uint16_t* __restrict__ qb, const uint16_t* __restrict__ kb,
    const float* __restrict__ rnq, const float* __restrict__ rnk,
    float* __restrict__ lpT, float* __restrict__ gpm, float* __restrict__ gpl)
{
    __shared__ __align__(16) uint16_t lds_q[BM * QSTR];  // 67584 B
    __shared__ __align__(16) uint16_t lds_k[BN * KSTR];  // 10240 B  (total 76 KB -> 2 blocks/CU)

    const int tid    = threadIdx.x;
    const int wave   = tid >> 6;
    const int lane   = tid & 63;
    const int quad   = lane >> 4;
    const int lanelo = lane & 15;
    const int wr     = wave >> 1;   // row half (0/1)
    const int wc     = wave & 1;    // col half (0/1)
    const int rowBase       = blockIdx.x * BM;
    const int colGroupBase  = blockIdx.y * COLS_PER_GROUP;

    // Stage the whole Q tile (128 x 256 bf16) once; reused across all j-tiles.
    #pragma unroll
    for (int it = 0; it < 16; ++it) {
        int c = it * 256 + tid;
        int row = c >> 5, ch = c & 31;
        uint4 d = ((const uint4*)qb)[(size_t)(rowBase + row) * (DDIM / 8) + ch];
        *(uint4*)&lds_q[row * QSTR + ch * 8] = d;
    }

    // Per-row scale = rnq[row] / T, for the 16 rows this lane touches in C-layout.
    float arow[16];
    #pragma unroll
    for (int mt = 0; mt < 4; ++mt)
        #pragma unroll
        for (int rg = 0; rg < 4; ++rg)
            arow[mt * 4 + rg] = rnq[rowBase + wr * 64 + mt * 16 + quad * 4 + rg] * INV_T;

    float m_run[16], l_run[16];
    #pragma unroll
    for (int i = 0; i < 16; ++i) { m_run[i] = -INFINITY; l_run[i] = 0.f; }

    for (int jt = 0; jt < COLS_PER_GROUP / BN; ++jt) {
        const int colT = colGroupBase + jt * BN;

        f32x4 acc[4][4];
        #pragma unroll
        for (int mt = 0; mt < 4; ++mt)
            #pragma unroll
            for (int nt = 0; nt < 4; ++nt)
                acc[mt][nt] = (f32x4){0.f, 0.f, 0.f, 0.f};

        #pragma unroll
        for (int kk = 0; kk < DDIM / 32; ++kk) {
            __syncthreads();   // previous chunk's reads done before overwrite
            // Stage K chunk: 128 rows x 32 cols bf16 (512 x 16B chunks, 2/thread)
            #pragma unroll
            for (int it = 0; it < 2; ++it) {
                int c = it * 256 + tid;
                int row = c >> 2, ch = c & 3;
                uint4 d = ((const uint4*)kb)[(size_t)(colT + row) * (DDIM / 8) + kk * 4 + ch];
                *(uint4*)&lds_k[row * KSTR + ch * 8] = d;
            }
            __syncthreads();

            bf16x8 av[4], bv[4];
            #pragma unroll
            for (int mt = 0; mt < 4; ++mt)
                av[mt] = *(const bf16x8*)&lds_q[(wr * 64 + mt * 16 + lanelo) * QSTR + kk * 32 + quad * 8];
            #pragma unroll
            for (int nt = 0; nt < 4; ++nt)
                bv[nt] = *(const bf16x8*)&lds_k[(wc * 64 + nt * 16 + lanelo) * KSTR + quad * 8];
            #pragma unroll
            for (int mt = 0; mt < 4; ++mt)
                #pragma unroll
                for (int nt = 0; nt < 4; ++nt)
                    acc[mt][nt] = __builtin_amdgcn_mfma_f32_16x16x32_bf16(av[mt], bv[nt], acc[mt][nt], 0, 0, 0);
        }

        // Epilogue: logits, diag handling, per-row online (m, l) update.
        float rnkc[4]; int gcol[4];
        #pragma unroll
        for (int nt = 0; nt < 4; ++nt) {
            gcol[nt] = colT + wc * 64 + nt * 16 + lanelo;
            rnkc[nt] = rnk[gcol[nt]];
        }
        #pragma unroll
        for (int mt = 0; mt < 4; ++mt) {
            int growb = rowBase + wr * 64 + mt * 16 + quad * 4;
            #pragma unroll
            for (int rg = 0; rg < 4; ++rg) {
                int grow = growb + rg;
                float rs = arow[mt * 4 + rg];
                float v[4];
                #pragma unroll
                for (int nt = 0; nt < 4; ++nt) {
                    v[nt] = acc[mt][nt][rg] * rs * rnkc[nt];
                    if (grow == gcol[nt]) { lpT[grow] = v[nt]; v[nt] = DIAG_LOGIT; }
                }
                float mt_ = fmaxf(fmaxf(v[0], v[1]), fmaxf(v[2], v[3]));
                #pragma unroll
                for (int m = 1; m < 16; m <<= 1) mt_ = fmaxf(mt_, __shfl_xor(mt_, m, 64));
                float p = __expf(v[0] - mt_) + __expf(v[1] - mt_) + __expf(v[2] - mt_) + __expf(v[3] - mt_);
                #pragma unroll
                for (int m = 1; m < 16; m <<= 1) p += __shfl_xor(p, m, 64);
                int i = mt * 4 + rg;
                float mo = m_run[i];
                float mn = fmaxf(mo, mt_);
                l_run[i] = l_run[i] * __expf(mo - mn) + p * __expf(mt_ - mn);
                m_run[i] = mn;
            }
        }
    }

    // Merge the two column-half waves per row; write block partial (m, l).
    __syncthreads();
    float* pm = (float*)lds_k;      // reuse: 512 floats needed, 10240 B available
    float* pl = pm + 256;
    if (lanelo == 0) {
        #pragma unroll
        for (int mt = 0; mt < 4; ++mt)
            #pragma unroll
            for (int rg = 0; rg < 4; ++rg) {
                int lr = wr * 64 + mt * 16 + quad * 4 + rg;
                pm[wc * 128 + lr] = m_run[mt * 4 + rg];
                pl[wc * 128 + lr] = l_run[mt * 4 + rg];
            }
    }
    __syncthreads();
    if (tid < 128) {
        float m0 = pm[tid], m1 = pm[128 + tid];
        float l0 = pl[tid], l1 = pl[128 + tid];
        float M = fmaxf(m0, m1);
        float L = l0 * __expf(m0 - M) + l1 * __expf(m1 - M);
        size_t o = (size_t)blockIdx.y * NROWS + rowBase + tid;
        gpm[o] = M; gpl[o] = L;
    }
}

// Kernel 3: merge GJ partials + l_pos term; loss = LSE - l_pos/T.
__global__ __launch_bounds__(256) void finalize_kernel(
    const float* __restrict__ gpm, const float* __restrict__ gpl,
    const float* __restrict__ lpT, float* __restrict__ out)
{
    int t = blockIdx.x * 256 + threadIdx.x;
    if (t >= NROWS) return;
    float M = -INFINITY;
    #pragma unroll
    for (int g = 0; g < GJ; ++g) M = fmaxf(M, gpm[g * NROWS + t]);
    float L = 0.f;
    #pragma unroll
    for (int g = 0; g < GJ; ++g) L += gpl[g * NROWS + t] * __expf(gpm[g * NROWS + t] - M);
    float lp = lpT[t];
    float M2 = fmaxf(M, lp);
    float L2 = L * __expf(M - M2) + __expf(lp - M2);
    out[t] = M2 + __logf(L2) - lp;
}

extern "C" void kernel_launch(void* const* d_in, const int* in_sizes, int n_in,
                              void* d_out, int out_size, void* d_ws, size_t ws_size,
                              hipStream_t stream) {
    const float* fq = (const float*)d_in[0];
    const float* fk = (const float*)d_in[1];
    char* ws = (char*)d_ws;
    // layout: qb 4MB | kb 4MB | rnq 32KB | rnk 32KB | lpT 32KB | gpm 256KB | gpl 256KB
    uint16_t* qb  = (uint16_t*)(ws);
    uint16_t* kb  = (uint16_t*)(ws + 4194304);
    float*    rnq = (float*)(ws + 8388608);
    float*    rnk = (float*)(ws + 8421376);
    float*    lpT = (float*)(ws + 8454144);
    float*    gpm = (float*)(ws + 8486912);
    float*    gpl = (float*)(ws + 8749056);

    norm_convert_kernel<<<(2 * NROWS) / 4, 256, 0, stream>>>(fq, fk, qb, kb, rnq, rnk);
    dim3 grid(NROWS / BM, GJ);
    nce_main_kernel<<<grid, 256, 0, stream>>>(qb, kb, rnq, rnk, lpT, gpm, gpl);
    finalize_kernel<<<NROWS / 256, 256, 0, stream>>>(gpm, gpl, lpT, (float*)d_out);
}

// Round 2
// 141.224 us; speedup vs baseline: 1.0899x; 1.0899x over previous
//
#include <hip/hip_runtime.h>
#include <stdint.h>
#include <math.h>

#define NROWS 8192
#define DDIM  256
#define BM    128
#define BN    128
#define GJ    8                         // column groups (grid.y)
#define COLS_PER_GROUP (NROWS / GJ)     // 1024
#define QSTR  264                       // lds row stride (bf16): 528B -> lane stride 4 dwords, 2-way banks (free)

constexpr float INV_T  = 1.0f / 0.07f;  // fixed LSE max M0 = INV_T (|logit| <= 1/T)
constexpr float LOG2E  = 1.44269504f;
constexpr float K1     = INV_T * LOG2E; // exp arg: (acc - 1) * INV_T * LOG2E = fma(acc, K1, -K1)

typedef __bf16 bf16x8 __attribute__((ext_vector_type(8)));
typedef float  f32x4  __attribute__((ext_vector_type(4)));

__device__ inline uint16_t f2bf(float f) {
    uint32_t u = __float_as_uint(f);
    u += 0x7fffu + ((u >> 16) & 1u);    // RNE
    return (uint16_t)(u >> 16);
}

// Kernel 1: normalize each row to unit length, emit bf16. One wave per row.
__global__ __launch_bounds__(256) void norm_convert_kernel(
    const float* __restrict__ fq, const float* __restrict__ fk,
    uint16_t* __restrict__ qb, uint16_t* __restrict__ kb)
{
    const int wave = threadIdx.x >> 6;
    const int lane = threadIdx.x & 63;
    const int row  = blockIdx.x * 4 + wave;

    const float* src; uint16_t* dstb;
    if (row < NROWS) {
        src = fq + (size_t)row * DDIM; dstb = qb + (size_t)row * DDIM;
    } else {
        int r = row - NROWS;
        src = fk + (size_t)r * DDIM; dstb = kb + (size_t)r * DDIM;
    }

    float4 v = ((const float4*)src)[lane];
    float ss = v.x*v.x + v.y*v.y + v.z*v.z + v.w*v.w;
    #pragma unroll
    for (int m = 1; m < 64; m <<= 1) ss += __shfl_xor(ss, m, 64);
    float r = rsqrtf(ss);   // norms ~16 for N(0,1) D=256; eps clamp unreachable

    ushort4 o;
    o.x = f2bf(v.x * r); o.y = f2bf(v.y * r); o.z = f2bf(v.z * r); o.w = f2bf(v.w * r);
    ((ushort4*)dstb)[lane] = o;
}

// Kernel 2: fixed-max fused GEMM + sum-of-exp over this block's 1024-col group.
// Q fragments live in registers (loaded via LDS once); the same LDS then holds
// full 128x256 K tiles (2 barriers per j-tile). Block: 4 waves in 2x2, 64x64/wave.
__global__ __launch_bounds__(256, 2) void nce_main_kernel(
    const uint16_t* __restrict__ qb, const uint16_t* __restrict__ kb,
    float* __restrict__ lpT, float* __restrict__ gpl)
{
    __shared__ __align__(16) uint16_t lds[BM * QSTR];   // 67584 B -> 2 blocks/CU

    const int tid    = threadIdx.x;
    const int wave   = tid >> 6;
    const int lane   = tid & 63;
    const int quad   = lane >> 4;
    const int lanelo = lane & 15;
    const int wr     = wave >> 1;
    const int wc     = wave & 1;
    const int rowBase      = blockIdx.x * BM;
    const int colGroupBase = blockIdx.y * COLS_PER_GROUP;

    // Stage Q tile (128x256 bf16) once, pull fragments to registers.
    #pragma unroll
    for (int it = 0; it < 16; ++it) {
        int c = it * 256 + tid;
        int row = c >> 5, ch = c & 31;
        uint4 d = ((const uint4*)qb)[(size_t)(rowBase + row) * 32 + ch];
        *(uint4*)&lds[row * QSTR + ch * 8] = d;
    }
    __syncthreads();

    bf16x8 aq[4][8];    // 128 VGPRs: rows (wr*64 + mt*16 + lanelo), k-chunks kk
    #pragma unroll
    for (int mt = 0; mt < 4; ++mt)
        #pragma unroll
        for (int kk = 0; kk < 8; ++kk)
            aq[mt][kk] = *(const bf16x8*)&lds[(wr * 64 + mt * 16 + lanelo) * QSTR + kk * 32 + quad * 8];

    float l_run[16];
    #pragma unroll
    for (int i = 0; i < 16; ++i) l_run[i] = 0.f;

    for (int jt = 0; jt < COLS_PER_GROUP / BN; ++jt) {
        const int colT = colGroupBase + jt * BN;

        __syncthreads();    // Q frags read (jt=0) / previous K reads done
        #pragma unroll
        for (int it = 0; it < 16; ++it) {
            int c = it * 256 + tid;
            int row = c >> 5, ch = c & 31;
            uint4 d = ((const uint4*)kb)[(size_t)(colT + row) * 32 + ch];
            *(uint4*)&lds[row * QSTR + ch * 8] = d;
        }
        __syncthreads();

        f32x4 acc[4][4];
        #pragma unroll
        for (int mt = 0; mt < 4; ++mt)
            #pragma unroll
            for (int nt = 0; nt < 4; ++nt)
                acc[mt][nt] = (f32x4){0.f, 0.f, 0.f, 0.f};

        #pragma unroll
        for (int kk = 0; kk < 8; ++kk) {
            bf16x8 bv[4];
            #pragma unroll
            for (int nt = 0; nt < 4; ++nt)
                bv[nt] = *(const bf16x8*)&lds[(wc * 64 + nt * 16 + lanelo) * QSTR + kk * 32 + quad * 8];
            #pragma unroll
            for (int mt = 0; mt < 4; ++mt)
                #pragma unroll
                for (int nt = 0; nt < 4; ++nt)
                    acc[mt][nt] = __builtin_amdgcn_mfma_f32_16x16x32_bf16(aq[mt][kk], bv[nt], acc[mt][nt], 0, 0, 0);
        }

        // Epilogue: fixed-max exp accumulate, no cross-lane traffic.
        int gcol[4];
        #pragma unroll
        for (int nt = 0; nt < 4; ++nt) gcol[nt] = colT + wc * 64 + nt * 16 + lanelo;
        #pragma unroll
        for (int mt = 0; mt < 4; ++mt) {
            #pragma unroll
            for (int rg = 0; rg < 4; ++rg) {
                int grow = rowBase + wr * 64 + mt * 16 + quad * 4 + rg;
                float s = 0.f;
                #pragma unroll
                for (int nt = 0; nt < 4; ++nt) {
                    float a = acc[mt][nt][rg];
                    float e = exp2f(fmaf(a, K1, -K1));
                    if (grow == gcol[nt]) { lpT[grow] = a * INV_T; e = 0.f; }  // diag: e^(-157) ~ 0
                    s += e;
                }
                l_run[mt * 4 + rg] += s;
            }
        }
    }

    // One-time cross-lane reduce over the 16 lanelo lanes (same row, different cols).
    #pragma unroll
    for (int i = 0; i < 16; ++i) {
        float v = l_run[i];
        v += __shfl_xor(v, 1, 64);
        v += __shfl_xor(v, 2, 64);
        v += __shfl_xor(v, 4, 64);
        v += __shfl_xor(v, 8, 64);
        l_run[i] = v;
    }
    __syncthreads();
    float* pl = (float*)lds;    // 256 floats needed
    if (lanelo == 0) {
        #pragma unroll
        for (int mt = 0; mt < 4; ++mt)
            #pragma unroll
            for (int rg = 0; rg < 4; ++rg) {
                int lr = wr * 64 + mt * 16 + quad * 4 + rg;
                pl[wc * 128 + lr] = l_run[mt * 4 + rg];
            }
    }
    __syncthreads();
    if (tid < 128) {
        float L = pl[tid] + pl[128 + tid];
        gpl[(size_t)blockIdx.y * NROWS + rowBase + tid] = L;
    }
}

// Kernel 3: merge GJ partial sums + l_pos; loss = M0 + log(L) - l_pos/T.
__global__ __launch_bounds__(256) void finalize_kernel(
    const float* __restrict__ gpl, const float* __restrict__ lpT,
    float* __restrict__ out)
{
    int t = blockIdx.x * 256 + threadIdx.x;
    if (t >= NROWS) return;
    float L = 0.f;
    #pragma unroll
    for (int g = 0; g < GJ; ++g) L += gpl[g * NROWS + t];
    float lp = lpT[t];
    L += __expf(lp - INV_T);
    out[t] = INV_T + __logf(L) - lp;
}

extern "C" void kernel_launch(void* const* d_in, const int* in_sizes, int n_in,
                              void* d_out, int out_size, void* d_ws, size_t ws_size,
                              hipStream_t stream) {
    const float* fq = (const float*)d_in[0];
    const float* fk = (const float*)d_in[1];
    char* ws = (char*)d_ws;
    // layout: qb 4MB | kb 4MB | lpT 32KB | gpl 256KB
    uint16_t* qb  = (uint16_t*)(ws);
    uint16_t* kb  = (uint16_t*)(ws + 4194304);
    float*    lpT = (float*)(ws + 8388608);
    float*    gpl = (float*)(ws + 8421376);

    norm_convert_kernel<<<(2 * NROWS) / 4, 256, 0, stream>>>(fq, fk, qb, kb);
    dim3 grid(NROWS / BM, GJ);
    nce_main_kernel<<<grid, 256, 0, stream>>>(qb, kb, lpT, gpl);
    finalize_kernel<<<NROWS / 256, 256, 0, stream>>>(gpl, lpT, (float*)d_out);
}

// Round 3
// 111.773 us; speedup vs baseline: 1.3771x; 1.2635x over previous
//
#include <hip/hip_runtime.h>
#include <stdint.h>
#include <math.h>

#define NROWS 8192
#define DDIM  256
#define BM    128
#define BN    128
#define GJ    8                         // column groups (grid.y)
#define COLS_PER_GROUP (NROWS / GJ)     // 1024

constexpr float INV_T  = 1.0f / 0.07f;  // fixed LSE max M0 = 1/T (|logit| <= 1/T)
constexpr float LOG2E  = 1.44269504f;
constexpr float K1     = INV_T * LOG2E; // exp2 arg: fma(acc, K1, -K1)

typedef __bf16 bf16x8 __attribute__((ext_vector_type(8)));
typedef float  f32x4  __attribute__((ext_vector_type(4)));

__device__ __forceinline__ void async_copy16(const uint16_t* g, uint16_t* l) {
    __builtin_amdgcn_global_load_lds(
        (const __attribute__((address_space(1))) uint32_t*)g,
        (__attribute__((address_space(3))) uint32_t*)l, 16, 0, 0);
}

__device__ inline uint16_t f2bf(float f) {
    uint32_t u = __float_as_uint(f);
    u += 0x7fffu + ((u >> 16) & 1u);    // RNE
    return (uint16_t)(u >> 16);
}

// Kernel 1: normalize each row to unit length, emit bf16. One wave per row.
__global__ __launch_bounds__(256) void norm_convert_kernel(
    const float* __restrict__ fq, const float* __restrict__ fk,
    uint16_t* __restrict__ qb, uint16_t* __restrict__ kb)
{
    const int wave = threadIdx.x >> 6;
    const int lane = threadIdx.x & 63;
    const int row  = blockIdx.x * 4 + wave;

    const float* src; uint16_t* dstb;
    if (row < NROWS) {
        src = fq + (size_t)row * DDIM; dstb = qb + (size_t)row * DDIM;
    } else {
        int r = row - NROWS;
        src = fk + (size_t)r * DDIM; dstb = kb + (size_t)r * DDIM;
    }

    float4 v = ((const float4*)src)[lane];
    float ss = v.x*v.x + v.y*v.y + v.z*v.z + v.w*v.w;
    #pragma unroll
    for (int m = 1; m < 64; m <<= 1) ss += __shfl_xor(ss, m, 64);
    float r = rsqrtf(ss);

    ushort4 o;
    o.x = f2bf(v.x * r); o.y = f2bf(v.y * r); o.z = f2bf(v.z * r); o.w = f2bf(v.w * r);
    ((ushort4*)dstb)[lane] = o;
}

// Kernel 2: fused GEMM + fixed-max sum-of-exp over this block's 1024-col group.
// Q tile (128x256) in LDS (staged once, async); K in BK=32 double-buffered chunks
// (async, 1-phase pipeline slack). XOR source-swizzle kills ds_read row-stride
// conflicts. Block: 4 waves in 2x2, each 64x64 via 16x16x32 bf16 MFMA.
__global__ __launch_bounds__(256, 2) void nce_main_kernel(
    const uint16_t* __restrict__ qb, const uint16_t* __restrict__ kb,
    float* __restrict__ lpT, float* __restrict__ gpl)
{
    __shared__ __align__(16) uint16_t lds_q[BM * DDIM];     // 65536 B, swizzled
    __shared__ __align__(16) uint16_t lds_k[2 * BN * 32];   // 16384 B, 2 bufs, swizzled

    const int tid    = threadIdx.x;
    const int wave   = tid >> 6;
    const int lane   = tid & 63;
    const int quad   = lane >> 4;
    const int lanelo = lane & 15;
    const int wr     = wave >> 1;
    const int wc     = wave & 1;
    const int rowBase      = blockIdx.x * BM;
    const int colGroupBase = blockIdx.y * COLS_PER_GROUP;

    // ---- Stage Q tile once: 4096 chunks of 16B, 16 instrs/wave, source-swizzled.
    #pragma unroll
    for (int i = 0; i < 16; ++i) {
        int S   = (wave * 16 + i) * 64 + lane;          // lds chunk id
        int row = S >> 5;
        int ch  = (S & 31) ^ (row & 31);                // swizzle: source chunk
        async_copy16(qb + (size_t)(rowBase + row) * DDIM + ch * 8,
                     lds_q + (size_t)(wave * 16 + i) * 512);
    }

    // ---- K staging lane constants (chunk = 16B; 4 chunks per 32-col row).
    int kS0   = wave * 128 + lane;                      // i=0 chunk id in 512-chunk buffer
    int krow0 = kS0 >> 2;
    int kch0  = (lane & 3) ^ (krow0 & 3);
    int krow1 = (kS0 + 64) >> 2;
    int kch1  = (lane & 3) ^ (krow1 & 3);
    const uint16_t* kbase0 = kb + (size_t)(colGroupBase + krow0) * DDIM + kch0 * 8;
    const uint16_t* kbase1 = kb + (size_t)(colGroupBase + krow1) * DDIM + kch1 * 8;
    uint16_t* kl0 = lds_k + wave * 1024;                // wave-uniform dest (i=0)

    // phase 0 (jt=0, kk=0) into buf 0
    async_copy16(kbase0, kl0);
    async_copy16(kbase1, kl0 + 512);
    __syncthreads();    // Q + first K chunk visible

    // ---- Fragment address constants.
    int rq[4], rq31[4];
    #pragma unroll
    for (int mt = 0; mt < 4; ++mt) {
        rq[mt]   = wr * 64 + mt * 16 + lanelo;
        rq31[mt] = rq[mt] & 31;
    }
    int bvoff[4];
    #pragma unroll
    for (int nt = 0; nt < 4; ++nt) {
        int rk = wc * 64 + nt * 16 + lanelo;
        bvoff[nt] = rk * 32 + (quad ^ (rk & 3)) * 8;
    }

    float l_run[16];
    #pragma unroll
    for (int i = 0; i < 16; ++i) l_run[i] = 0.f;

    for (int jt = 0; jt < 8; ++jt) {
        const int colT = colGroupBase + jt * BN;

        f32x4 acc[4][4];
        #pragma unroll
        for (int mt = 0; mt < 4; ++mt)
            #pragma unroll
            for (int nt = 0; nt < 4; ++nt)
                acc[mt][nt] = (f32x4){0.f, 0.f, 0.f, 0.f};

        #pragma unroll
        for (int kk = 0; kk < 8; ++kk) {
            const int p    = (jt << 3) + kk;
            const int buf  = p & 1;
            const int nbuf = buf ^ 1;

            // Issue next chunk's loads (drained only at the NEXT barrier).
            if (p < 63) {
                int np  = p + 1;
                int off = ((np >> 3) << 15) + ((np & 7) << 5);  // njt*128*256 + nkk*32
                uint16_t* ld = lds_k + nbuf * 4096 + wave * 1024;
                async_copy16(kbase0 + off, ld);
                async_copy16(kbase1 + off, ld + 512);
            }

            // Compute on buf.
            bf16x8 av[4], bv[4];
            #pragma unroll
            for (int mt = 0; mt < 4; ++mt) {
                int chp = ((kk << 2) + quad) ^ rq31[mt];
                av[mt] = *(const bf16x8*)&lds_q[rq[mt] * 256 + chp * 8];
            }
            #pragma unroll
            for (int nt = 0; nt < 4; ++nt)
                bv[nt] = *(const bf16x8*)&lds_k[buf * 4096 + bvoff[nt]];
            #pragma unroll
            for (int mt = 0; mt < 4; ++mt)
                #pragma unroll
                for (int nt = 0; nt < 4; ++nt)
                    acc[mt][nt] = __builtin_amdgcn_mfma_f32_16x16x32_bf16(av[mt], bv[nt], acc[mt][nt], 0, 0, 0);

            __syncthreads();    // publish chunk p+1's writes / guard buf reuse
        }

        // Epilogue: fixed-max exp accumulate (registers only).
        int gcol[4];
        #pragma unroll
        for (int nt = 0; nt < 4; ++nt) gcol[nt] = colT + wc * 64 + nt * 16 + lanelo;
        #pragma unroll
        for (int mt = 0; mt < 4; ++mt) {
            #pragma unroll
            for (int rg = 0; rg < 4; ++rg) {
                int grow = rowBase + wr * 64 + mt * 16 + quad * 4 + rg;
                float s = 0.f;
                #pragma unroll
                for (int nt = 0; nt < 4; ++nt) {
                    float a = acc[mt][nt][rg];
                    float e = exp2f(fmaf(a, K1, -K1));
                    if (grow == gcol[nt]) { lpT[grow] = a * INV_T; e = 0.f; }  // diag term ~e^-157
                    s += e;
                }
                l_run[mt * 4 + rg] += s;
            }
        }
    }

    // Cross-lane reduce over the 16 lanelo lanes (same row, different cols).
    #pragma unroll
    for (int i = 0; i < 16; ++i) {
        float v = l_run[i];
        v += __shfl_xor(v, 1, 64);
        v += __shfl_xor(v, 2, 64);
        v += __shfl_xor(v, 4, 64);
        v += __shfl_xor(v, 8, 64);
        l_run[i] = v;
    }
    // All LDS reads/writes done (last barrier passed; no loads in flight).
    float* pl = (float*)lds_k;      // 256 floats scratch
    if (lanelo == 0) {
        #pragma unroll
        for (int mt = 0; mt < 4; ++mt)
            #pragma unroll
            for (int rg = 0; rg < 4; ++rg) {
                int lr = wr * 64 + mt * 16 + quad * 4 + rg;
                pl[wc * 128 + lr] = l_run[mt * 4 + rg];
            }
    }
    __syncthreads();
    if (tid < 128) {
        float L = pl[tid] + pl[128 + tid];
        gpl[(size_t)blockIdx.y * NROWS + rowBase + tid] = L;
    }
}

// Kernel 3: merge GJ partial sums + l_pos; loss = M0 + log(L) - l_pos/T.
__global__ __launch_bounds__(256) void finalize_kernel(
    const float* __restrict__ gpl, const float* __restrict__ lpT,
    float* __restrict__ out)
{
    int t = blockIdx.x * 256 + threadIdx.x;
    if (t >= NROWS) return;
    float L = 0.f;
    #pragma unroll
    for (int g = 0; g < GJ; ++g) L += gpl[g * NROWS + t];
    float lp = lpT[t];
    L += __expf(lp - INV_T);
    out[t] = INV_T + __logf(L) - lp;
}

extern "C" void kernel_launch(void* const* d_in, const int* in_sizes, int n_in,
                              void* d_out, int out_size, void* d_ws, size_t ws_size,
                              hipStream_t stream) {
    const float* fq = (const float*)d_in[0];
    const float* fk = (const float*)d_in[1];
    char* ws = (char*)d_ws;
    // layout: qb 4MB | kb 4MB | lpT 32KB | gpl 256KB
    uint16_t* qb  = (uint16_t*)(ws);
    uint16_t* kb  = (uint16_t*)(ws + 4194304);
    float*    lpT = (float*)(ws + 8388608);
    float*    gpl = (float*)(ws + 8421376);

    norm_convert_kernel<<<(2 * NROWS) / 4, 256, 0, stream>>>(fq, fk, qb, kb);
    dim3 grid(NROWS / BM, GJ);
    nce_main_kernel<<<grid, 256, 0, stream>>>(qb, kb, lpT, gpl);
    finalize_kernel<<<NROWS / 256, 256, 0, stream>>>(gpl, lpT, (float*)d_out);
}